// Round 1
// baseline (3119.225 us; speedup 1.0000x reference)
//
#include <hip/hip_runtime.h>
#include <stdint.h>

// Problem constants (fixed by the reference)
#define NN 50000
#define EE 800000
#define INDIM 1280
#define GD 512
#define CAT 1536
#define FC0D 1024
#define FC1D 512
#define OUTD 256
#define NG 64

// ---------------- utility kernels ----------------
__global__ void zero_u32(uint32_t* p, int n) {
    int i = blockIdx.x * 256 + threadIdx.x;
    if (i < n) p[i] = 0u;
}

__global__ void count_edges(const int* __restrict__ ei, int* __restrict__ cnt) {
    int e = blockIdx.x * 256 + threadIdx.x;
    if (e < EE) atomicAdd(&cnt[ei[EE + e]], 1);
}

__global__ __launch_bounds__(1024) void scan1(const int* __restrict__ cnt,
                                              int* __restrict__ row_ptr,
                                              int* __restrict__ bsum, int n) {
    __shared__ int s[1024];
    int tid = threadIdx.x;
    int i = blockIdx.x * 1024 + tid;
    int v = (i < n) ? cnt[i] : 0;
    s[tid] = v;
    __syncthreads();
    for (int off = 1; off < 1024; off <<= 1) {
        int t = 0;
        if (tid >= off) t = s[tid - off];
        __syncthreads();
        if (tid >= off) s[tid] += t;
        __syncthreads();
    }
    if (i < n) row_ptr[i] = s[tid] - v;   // block-local exclusive
    if (tid == 1023) bsum[blockIdx.x] = s[1023];
}

__global__ void scan2(int* bsum, int nb) {
    if (threadIdx.x == 0 && blockIdx.x == 0) {
        int run = 0;
        for (int b = 0; b < nb; b++) { int t = bsum[b]; bsum[b] = run; run += t; }
    }
}

__global__ __launch_bounds__(1024) void scan3(int* __restrict__ row_ptr,
                                              const int* __restrict__ bsum, int n) {
    int i = blockIdx.x * 1024 + threadIdx.x;
    if (i < n) row_ptr[i] += bsum[blockIdx.x];
    if (i == 0) row_ptr[n] = EE;
}

__global__ void compute_dinv(const int* __restrict__ cnt, float* __restrict__ dinv) {
    int i = blockIdx.x * 256 + threadIdx.x;
    if (i < NN) dinv[i] = rsqrtf((float)cnt[i] + 1.0f);
}

__global__ void copy_fill(const int* __restrict__ row_ptr, int* __restrict__ fill) {
    int i = blockIdx.x * 256 + threadIdx.x;
    if (i < NN) fill[i] = row_ptr[i];
}

__global__ void scatter_edges(const int* __restrict__ ei, int* __restrict__ fill,
                              int* __restrict__ col) {
    int e = blockIdx.x * 256 + threadIdx.x;
    if (e < EE) {
        int s = ei[e];
        int d = ei[EE + e];
        int pos = atomicAdd(&fill[d], 1);
        col[pos] = s;
    }
}

__global__ void count_batch(const int* __restrict__ batch, int* __restrict__ gcnt) {
    int i = blockIdx.x * 256 + threadIdx.x;
    if (i < NN) atomicAdd(&gcnt[batch[i]], 1);
}

__global__ void gscan(const int* __restrict__ gcnt, int* __restrict__ goff) {
    if (threadIdx.x == 0 && blockIdx.x == 0) {
        int r = 0;
        for (int g = 0; g < NG; g++) { goff[g] = r; r += gcnt[g]; }
        goff[NG] = r;
    }
}

// ---------------- fp32 tiled GEMM: C[M x Nout] = A[M x K] @ W[K x Nout] ----------------
#define BM 128
#define BN 128
#define BK 16

__global__ __launch_bounds__(256) void gemm_f32(const float* __restrict__ A,
                                                const float* __restrict__ W,
                                                float* __restrict__ C,
                                                int M, int K, int Nout) {
    __shared__ float a_s[BK][BM + 4];   // [k][m], row stride 132 floats (528B, 16B-aligned)
    __shared__ float w_s[BK][BN + 4];   // [k][n]
    int tid = threadIdx.x;
    int tx = tid & 15, ty = tid >> 4;
    int bm = blockIdx.x * BM, bn = blockIdx.y * BN;

    float acc[8][8];
#pragma unroll
    for (int r = 0; r < 8; r++)
#pragma unroll
        for (int c = 0; c < 8; c++) acc[r][c] = 0.f;

    for (int k0 = 0; k0 < K; k0 += BK) {
        // A tile: 128x16 = 512 float4s, transposed into a_s[k][m]
#pragma unroll
        for (int i = 0; i < 2; i++) {
            int idx = tid + i * 256;      // 0..511
            int row = idx >> 2;
            int c4 = idx & 3;
            int gr = bm + row;
            float4 v = make_float4(0.f, 0.f, 0.f, 0.f);
            if (gr < M) v = *(const float4*)(A + (size_t)gr * K + k0 + c4 * 4);
            a_s[c4 * 4 + 0][row] = v.x;
            a_s[c4 * 4 + 1][row] = v.y;
            a_s[c4 * 4 + 2][row] = v.z;
            a_s[c4 * 4 + 3][row] = v.w;
        }
        // W tile: 16x128 = 512 float4s, direct
#pragma unroll
        for (int i = 0; i < 2; i++) {
            int idx = tid + i * 256;
            int row = idx >> 5;
            int c4 = idx & 31;
            *(float4*)(&w_s[row][c4 * 4]) =
                *(const float4*)(W + (size_t)(k0 + row) * Nout + bn + c4 * 4);
        }
        __syncthreads();
#pragma unroll
        for (int kk = 0; kk < BK; kk++) {
            float4 a0 = *(const float4*)(&a_s[kk][ty * 8]);
            float4 a1 = *(const float4*)(&a_s[kk][ty * 8 + 4]);
            float4 w0 = *(const float4*)(&w_s[kk][tx * 8]);
            float4 w1 = *(const float4*)(&w_s[kk][tx * 8 + 4]);
            float av[8] = {a0.x, a0.y, a0.z, a0.w, a1.x, a1.y, a1.z, a1.w};
            float wv[8] = {w0.x, w0.y, w0.z, w0.w, w1.x, w1.y, w1.z, w1.w};
#pragma unroll
            for (int r = 0; r < 8; r++)
#pragma unroll
                for (int c = 0; c < 8; c++)
                    acc[r][c] = fmaf(av[r], wv[c], acc[r][c]);
        }
        __syncthreads();
    }
#pragma unroll
    for (int r = 0; r < 8; r++) {
        int gr = bm + ty * 8 + r;
        if (gr < M) {
            float4 o0 = make_float4(acc[r][0], acc[r][1], acc[r][2], acc[r][3]);
            float4 o1 = make_float4(acc[r][4], acc[r][5], acc[r][6], acc[r][7]);
            *(float4*)(C + (size_t)gr * Nout + bn + tx * 8) = o0;
            *(float4*)(C + (size_t)gr * Nout + bn + tx * 8 + 4) = o1;
        }
    }
}

// ---------------- GCN aggregation: out[row] = h[row]/deg + sum_nbr h[src]*dinv[src]*dinv[row] + b
__global__ __launch_bounds__(256) void agg_kernel(const float* __restrict__ h,
                                                  float* __restrict__ out,
                                                  const int* __restrict__ row_ptr,
                                                  const int* __restrict__ col,
                                                  const float* __restrict__ dinv,
                                                  const float* __restrict__ bias) {
    int row = blockIdx.x;
    int tid = threadIdx.x;   // 256 threads, float2 each -> 512 dims
    float di = dinv[row];
    float2 hv = ((const float2*)(h + (size_t)row * GD))[tid];
    float self = di * di;
    float acc0 = hv.x * self, acc1 = hv.y * self;
    int s = row_ptr[row], e = row_ptr[row + 1];
    __shared__ int scol[64];
    __shared__ float snorm[64];
    for (int base = s; base < e; base += 64) {
        int m = min(64, e - base);
        __syncthreads();
        if (tid < m) {
            int c = col[base + tid];
            scol[tid] = c;
            snorm[tid] = dinv[c] * di;
        }
        __syncthreads();
        for (int j = 0; j < m; j++) {
            float2 v = ((const float2*)(h + (size_t)scol[j] * GD))[tid];
            float w = snorm[j];
            acc0 = fmaf(v.x, w, acc0);
            acc1 = fmaf(v.y, w, acc1);
        }
    }
    float2 b2 = ((const float2*)bias)[tid];
    float2 o;
    o.x = acc0 + b2.x;
    o.y = acc1 + b2.y;
    ((float2*)(out + (size_t)row * GD))[tid] = o;
}

// ---------------- mean-pool (sum phase, atomic into gsum) ----------------
#define PCH 8
__global__ void pool_kernel(const float* __restrict__ h, const int* __restrict__ goff,
                            float* __restrict__ gsum, int coloff) {
    int g = blockIdx.x;
    int c = blockIdx.y;
    int tid = threadIdx.x;
    int s = goff[g], e = goff[g + 1];
    long long len = e - s;
    int cs = s + (int)(len * c / PCH);
    int ce = s + (int)(len * (c + 1) / PCH);
    float a0 = 0.f, a1 = 0.f;
    for (int i = cs; i < ce; i++) {
        float2 v = ((const float2*)(h + (size_t)i * GD))[tid];
        a0 += v.x;
        a1 += v.y;
    }
    atomicAdd(&gsum[(size_t)g * CAT + coloff + tid * 2], a0);
    atomicAdd(&gsum[(size_t)g * CAT + coloff + tid * 2 + 1], a1);
}

__global__ void gdiv(float* __restrict__ gsum, const int* __restrict__ gcnt) {
    int i = blockIdx.x * 256 + threadIdx.x;
    if (i < NG * CAT) {
        int g = i / CAT;
        int c = gcnt[g];
        gsum[i] *= 1.0f / (float)(c > 0 ? c : 1);
    }
}

// ---------------- small FC: out[64 x NOUT] = act(A[64 x K] @ W + b) ----------------
template <int K, int NOUT, bool RELU>
__global__ __launch_bounds__(256) void fc_kernel(const float* __restrict__ A,
                                                 const float* __restrict__ W,
                                                 const float* __restrict__ bias,
                                                 float* __restrict__ out) {
    __shared__ float a_s[64][33];
    int tid = threadIdx.x;
    int c = blockIdx.x * 64 + (tid & 63);
    int grp = tid >> 6;    // 0..3 -> graphs grp*16..grp*16+15
    float acc[16];
#pragma unroll
    for (int i = 0; i < 16; i++) acc[i] = 0.f;
    for (int k0 = 0; k0 < K; k0 += 32) {
        __syncthreads();
#pragma unroll
        for (int i = 0; i < 8; i++) {
            int idx = tid + i * 256;   // 0..2047
            int m = idx >> 5, kk = idx & 31;
            a_s[m][kk] = A[(size_t)m * K + k0 + kk];
        }
        __syncthreads();
#pragma unroll
        for (int kk = 0; kk < 32; kk++) {
            float w = W[(size_t)(k0 + kk) * NOUT + c];
#pragma unroll
            for (int i = 0; i < 16; i++)
                acc[i] = fmaf(a_s[grp * 16 + i][kk], w, acc[i]);
        }
    }
    float b = bias[c];
#pragma unroll
    for (int i = 0; i < 16; i++) {
        float v = acc[i] + b;
        if (RELU) v = fmaxf(v, 0.f);
        out[(size_t)(grp * 16 + i) * NOUT + c] = v;
    }
}

// ---------------- launch ----------------
static inline size_t al256(size_t x) { return (x + 255) & ~(size_t)255; }

extern "C" void kernel_launch(void* const* d_in, const int* in_sizes, int n_in,
                              void* d_out, int out_size, void* d_ws, size_t ws_size,
                              hipStream_t stream) {
    const float* x   = (const float*)d_in[0];
    const int*   ei  = (const int*)d_in[1];
    const int*   bat = (const int*)d_in[2];
    const float* Wg1 = (const float*)d_in[3];
    const float* bg1 = (const float*)d_in[4];
    const float* Wg2 = (const float*)d_in[5];
    const float* bg2 = (const float*)d_in[6];
    const float* Wg3 = (const float*)d_in[7];
    const float* bg3 = (const float*)d_in[8];
    const float* Wr  = (const float*)d_in[9];
    const float* br  = (const float*)d_in[10];
    const float* Wf  = (const float*)d_in[11];
    const float* bf  = (const float*)d_in[12];
    const float* Wo  = (const float*)d_in[13];
    const float* bo  = (const float*)d_in[14];
    float* out = (float*)d_out;

    char* ws = (char*)d_ws;
    size_t off = 0;
    float* B0 = (float*)(ws + off); off += al256((size_t)NN * GD * 4);
    float* B1 = (float*)(ws + off); off += al256((size_t)NN * GD * 4);
    int*   cnt = (int*)(ws + off); off += al256((size_t)NN * 4);
    int*   row_ptr = (int*)(ws + off); off += al256((size_t)(NN + 1) * 4);
    int*   fill = (int*)(ws + off); off += al256((size_t)NN * 4);
    float* dinv = (float*)(ws + off); off += al256((size_t)NN * 4);
    int*   col = (int*)(ws + off); off += al256((size_t)EE * 4);
    int*   bsum = (int*)(ws + off); off += al256(64 * 4);
    int*   gcnt = (int*)(ws + off); off += al256(NG * 4);
    int*   goff = (int*)(ws + off); off += al256((NG + 1) * 4);
    float* gsum = (float*)(ws + off); off += al256((size_t)NG * CAT * 4);
    float* r0 = (float*)(ws + off); off += al256((size_t)NG * FC0D * 4);
    float* r1 = (float*)(ws + off); off += al256((size_t)NG * FC1D * 4);
    (void)ws_size; (void)n_in; (void)in_sizes; (void)out_size;

    const int nscan = (NN + 1023) / 1024;   // 49

    // zero: cnt, gcnt, gsum
    zero_u32<<<dim3((NN + 255) / 256), 256, 0, stream>>>((uint32_t*)cnt, NN);
    zero_u32<<<dim3(1), 256, 0, stream>>>((uint32_t*)gcnt, NG);
    zero_u32<<<dim3((NG * CAT + 255) / 256), 256, 0, stream>>>((uint32_t*)gsum, NG * CAT);

    // CSR build (by dst)
    count_edges<<<dim3((EE + 255) / 256), 256, 0, stream>>>(ei, cnt);
    scan1<<<dim3(nscan), 1024, 0, stream>>>(cnt, row_ptr, bsum, NN);
    scan2<<<dim3(1), 64, 0, stream>>>(bsum, nscan);
    scan3<<<dim3(nscan), 1024, 0, stream>>>(row_ptr, bsum, NN);
    compute_dinv<<<dim3((NN + 255) / 256), 256, 0, stream>>>(cnt, dinv);
    copy_fill<<<dim3((NN + 255) / 256), 256, 0, stream>>>(row_ptr, fill);
    scatter_edges<<<dim3((EE + 255) / 256), 256, 0, stream>>>(ei, fill, col);

    // graph segments
    count_batch<<<dim3((NN + 255) / 256), 256, 0, stream>>>(bat, gcnt);
    gscan<<<dim3(1), 64, 0, stream>>>(gcnt, goff);

    dim3 ggrid((NN + BM - 1) / BM, GD / BN);
    dim3 agrid(NN);
    dim3 pgrid(NG, PCH);

    // Layer 1
    gemm_f32<<<ggrid, 256, 0, stream>>>(x, Wg1, B0, NN, INDIM, GD);
    agg_kernel<<<agrid, 256, 0, stream>>>(B0, B1, row_ptr, col, dinv, bg1);
    pool_kernel<<<pgrid, 256, 0, stream>>>(B1, goff, gsum, 0);
    // Layer 2
    gemm_f32<<<ggrid, 256, 0, stream>>>(B1, Wg2, B0, NN, GD, GD);
    agg_kernel<<<agrid, 256, 0, stream>>>(B0, B1, row_ptr, col, dinv, bg2);
    pool_kernel<<<pgrid, 256, 0, stream>>>(B1, goff, gsum, GD);
    // Layer 3
    gemm_f32<<<ggrid, 256, 0, stream>>>(B1, Wg3, B0, NN, GD, GD);
    agg_kernel<<<agrid, 256, 0, stream>>>(B0, B1, row_ptr, col, dinv, bg3);
    pool_kernel<<<pgrid, 256, 0, stream>>>(B1, goff, gsum, 2 * GD);

    // mean
    gdiv<<<dim3((NG * CAT + 255) / 256), 256, 0, stream>>>(gsum, gcnt);

    // FC head
    fc_kernel<CAT, FC0D, true><<<dim3(FC0D / 64), 256, 0, stream>>>(gsum, Wr, br, r0);
    fc_kernel<FC0D, FC1D, true><<<dim3(FC1D / 64), 256, 0, stream>>>(r0, Wf, bf, r1);
    fc_kernel<FC1D, OUTD, false><<<dim3(OUTD / 64), 256, 0, stream>>>(r1, Wo, bo, out);
}

// Round 2
// 2160.472 us; speedup vs baseline: 1.4438x; 1.4438x over previous
//
#include <hip/hip_runtime.h>
#include <stdint.h>

// Problem constants (fixed by the reference)
#define NN 50000
#define EE 800000
#define INDIM 1280
#define GD 512
#define CAT 1536
#define FC0D 1024
#define FC1D 512
#define OUTD 256
#define NG 64

typedef __attribute__((ext_vector_type(8))) __bf16 bf16x8;
typedef __attribute__((ext_vector_type(4))) float f32x4;

// ---------------- helpers ----------------
__device__ __forceinline__ void split_bf16(float f, unsigned short& h, unsigned short& l) {
    unsigned int u = __builtin_bit_cast(unsigned int, f);
    h = (unsigned short)(u >> 16);                       // truncated hi
    float hf = __builtin_bit_cast(float, u & 0xffff0000u);
    float lf = f - hf;                                   // exact residual
    unsigned int ul = __builtin_bit_cast(unsigned int, lf);
    ul = ul + 0x7fffu + ((ul >> 16) & 1u);               // RNE lo
    l = (unsigned short)(ul >> 16);
}

__device__ __forceinline__ float bf2f(unsigned short s) {
    return __builtin_bit_cast(float, (unsigned int)s << 16);
}

__device__ __forceinline__ void g2l16(const void* g, void* l) {
    __builtin_amdgcn_global_load_lds(
        (const __attribute__((address_space(1))) void*)g,
        (__attribute__((address_space(3))) void*)l, 16, 0, 0);
}

// ---------------- utility kernels ----------------
__global__ void zero_u32(uint32_t* p, int n) {
    int i = blockIdx.x * 256 + threadIdx.x;
    if (i < n) p[i] = 0u;
}

__global__ void count_edges(const int* __restrict__ ei, int* __restrict__ cnt) {
    int e = blockIdx.x * 256 + threadIdx.x;
    if (e < EE) atomicAdd(&cnt[ei[EE + e]], 1);
}

__global__ __launch_bounds__(1024) void scan1(const int* __restrict__ cnt,
                                              int* __restrict__ row_ptr,
                                              int* __restrict__ bsum, int n) {
    __shared__ int s[1024];
    int tid = threadIdx.x;
    int i = blockIdx.x * 1024 + tid;
    int v = (i < n) ? cnt[i] : 0;
    s[tid] = v;
    __syncthreads();
    for (int off = 1; off < 1024; off <<= 1) {
        int t = 0;
        if (tid >= off) t = s[tid - off];
        __syncthreads();
        if (tid >= off) s[tid] += t;
        __syncthreads();
    }
    if (i < n) row_ptr[i] = s[tid] - v;
    if (tid == 1023) bsum[blockIdx.x] = s[1023];
}

__global__ void scan2(int* bsum, int nb) {
    if (threadIdx.x == 0 && blockIdx.x == 0) {
        int run = 0;
        for (int b = 0; b < nb; b++) { int t = bsum[b]; bsum[b] = run; run += t; }
    }
}

__global__ __launch_bounds__(1024) void scan3(int* __restrict__ row_ptr,
                                              const int* __restrict__ bsum, int n) {
    int i = blockIdx.x * 1024 + threadIdx.x;
    if (i < n) row_ptr[i] += bsum[blockIdx.x];
    if (i == 0) row_ptr[n] = EE;
}

__global__ void compute_dinv(const int* __restrict__ cnt, float* __restrict__ dinv) {
    int i = blockIdx.x * 256 + threadIdx.x;
    if (i < NN) dinv[i] = rsqrtf((float)cnt[i] + 1.0f);
}

__global__ void copy_fill(const int* __restrict__ row_ptr, int* __restrict__ fill) {
    int i = blockIdx.x * 256 + threadIdx.x;
    if (i < NN) fill[i] = row_ptr[i];
}

__global__ void scatter_edges(const int* __restrict__ ei, int* __restrict__ fill,
                              int* __restrict__ col) {
    int e = blockIdx.x * 256 + threadIdx.x;
    if (e < EE) {
        int s = ei[e];
        int d = ei[EE + e];
        int pos = atomicAdd(&fill[d], 1);
        col[pos] = s;
    }
}

__global__ void count_batch(const int* __restrict__ batch, int* __restrict__ gcnt) {
    int i = blockIdx.x * 256 + threadIdx.x;
    if (i < NN) atomicAdd(&gcnt[batch[i]], 1);
}

__global__ void gscan(const int* __restrict__ gcnt, int* __restrict__ goff) {
    if (threadIdx.x == 0 && blockIdx.x == 0) {
        int r = 0;
        for (int g = 0; g < NG; g++) { goff[g] = r; r += gcnt[g]; }
        goff[NG] = r;
    }
}

// ---------------- split fp32 -> bf16 hi/lo (flat) ----------------
__global__ void split_x_kernel(const float* __restrict__ x,
                               unsigned short* __restrict__ hi,
                               unsigned short* __restrict__ lo, int n4) {
    int stride = gridDim.x * 256;
    for (int i = blockIdx.x * 256 + threadIdx.x; i < n4; i += stride) {
        float4 v = ((const float4*)x)[i];
        ushort4 h4, l4;
        split_bf16(v.x, h4.x, l4.x);
        split_bf16(v.y, h4.y, l4.y);
        split_bf16(v.z, h4.z, l4.z);
        split_bf16(v.w, h4.w, l4.w);
        ((ushort4*)hi)[i] = h4;
        ((ushort4*)lo)[i] = l4;
    }
}

// ---------------- W [K][512] -> Wt hi/lo [512][K] (transpose + split) ----------------
__global__ __launch_bounds__(256) void tsplit_kernel(const float* __restrict__ W,
                                                     unsigned short* __restrict__ Thi,
                                                     unsigned short* __restrict__ Tlo,
                                                     int K) {
    __shared__ float t[32][33];
    int k0 = blockIdx.x * 32, n0 = blockIdx.y * 32;
    int r = threadIdx.x >> 3;
    int c4 = (threadIdx.x & 7) * 4;
    float4 v = *(const float4*)(W + (size_t)(k0 + r) * GD + n0 + c4);
    t[r][c4 + 0] = v.x;
    t[r][c4 + 1] = v.y;
    t[r][c4 + 2] = v.z;
    t[r][c4 + 3] = v.w;
    __syncthreads();
    ushort4 h4, l4;
    split_bf16(t[c4 + 0][r], h4.x, l4.x);
    split_bf16(t[c4 + 1][r], h4.y, l4.y);
    split_bf16(t[c4 + 2][r], h4.z, l4.z);
    split_bf16(t[c4 + 3][r], h4.w, l4.w);
    *(ushort4*)(Thi + (size_t)(n0 + r) * K + k0 + c4) = h4;
    *(ushort4*)(Tlo + (size_t)(n0 + r) * K + k0 + c4) = l4;
}

// ---------------- split-bf16 MFMA GEMM ----------------
// C[M x 512] = (Ahi+Alo)[M x K] @ (Whi+Wlo)[K x 512], W given transposed [512][K].
// Block tile 128(M) x 256(N), BK=32, 256 threads = 4 waves, wave tile 64x128.
#define GBM 128
#define GBN 256
#define GBK 32

__global__ __launch_bounds__(256, 2) void gemm_split(
    const unsigned short* __restrict__ Ahi, const unsigned short* __restrict__ Alo,
    const unsigned short* __restrict__ Whi, const unsigned short* __restrict__ Wlo,
    float* __restrict__ C, int M, int K) {
    __shared__ __align__(16) char sAh[GBM * GBK * 2];   // 8 KB
    __shared__ __align__(16) char sAl[GBM * GBK * 2];   // 8 KB
    __shared__ __align__(16) char sBh[GBN * GBK * 2];   // 16 KB
    __shared__ __align__(16) char sBl[GBN * GBK * 2];   // 16 KB

    const int tid = threadIdx.x;
    const int lane = tid & 63, wid = tid >> 6;
    const int wm = (wid >> 1) * 64;      // wave M offset (0 / 64)
    const int wn = (wid & 1) * 128;      // wave N offset (0 / 128)
    const int bm = blockIdx.x * GBM;
    const int bn = blockIdx.y * GBN;

    // --- staging source offsets (element units, bf16) ---
    // A: 512 segs of 16B (8 bf16). seg p: row=p>>2, ps=p&3, logical ks = ps ^ ((row>>1)&3)
    int ar0 = tid >> 2;
    int ak0 = ((tid & 3) ^ ((ar0 >> 1) & 3)) * 8;
    int ar1 = (tid + 256) >> 2;
    int ak1 = ((tid & 3) ^ ((ar1 >> 1) & 3)) * 8;
    unsigned int aoff0 = (unsigned int)min(bm + ar0, M - 1) * K + ak0;
    unsigned int aoff1 = (unsigned int)min(bm + ar1, M - 1) * K + ak1;
    // W: 1024 segs. seg p: row=p>>2 (0..255)
    unsigned int woff[4];
#pragma unroll
    for (int i = 0; i < 4; i++) {
        int p = tid + i * 256;
        int row = p >> 2;
        int ks = ((p & 3) ^ ((row >> 1) & 3)) * 8;
        woff[i] = (unsigned int)(bn + row) * K + ks;
    }

    // --- LDS read byte offsets (swizzled), loop-invariant ---
    int aRd[4], bRd[8];
#pragma unroll
    for (int mf = 0; mf < 4; mf++) {
        int row = wm + mf * 16 + (lane & 15);
        aRd[mf] = row * 64 + ((((lane >> 4)) ^ ((row >> 1) & 3)) << 4);
    }
#pragma unroll
    for (int nf = 0; nf < 8; nf++) {
        int row = wn + nf * 16 + (lane & 15);
        bRd[nf] = row * 64 + ((((lane >> 4)) ^ ((row >> 1) & 3)) << 4);
    }

    f32x4 acc[4][8];
#pragma unroll
    for (int mf = 0; mf < 4; mf++)
#pragma unroll
        for (int nf = 0; nf < 8; nf++) acc[mf][nf] = (f32x4)0.0f;

    const int ldsw = wid * 1024;   // per-wave LDS byte offset within a 4KB call-slab

    for (int k0 = 0; k0 < K; k0 += GBK) {
        __syncthreads();   // previous compute done before overwrite
        g2l16(Ahi + aoff0, sAh + ldsw);
        g2l16(Ahi + aoff1, sAh + 4096 + ldsw);
        g2l16(Alo + aoff0, sAl + ldsw);
        g2l16(Alo + aoff1, sAl + 4096 + ldsw);
#pragma unroll
        for (int i = 0; i < 4; i++) {
            g2l16(Whi + woff[i], sBh + i * 4096 + ldsw);
            g2l16(Wlo + woff[i], sBl + i * 4096 + ldsw);
        }
        aoff0 += GBK; aoff1 += GBK;
#pragma unroll
        for (int i = 0; i < 4; i++) woff[i] += GBK;
        __syncthreads();   // drains vmcnt -> LDS data ready

        bf16x8 ah[4], al[4];
#pragma unroll
        for (int mf = 0; mf < 4; mf++) {
            ah[mf] = *(const bf16x8*)(sAh + aRd[mf]);
            al[mf] = *(const bf16x8*)(sAl + aRd[mf]);
        }
#pragma unroll
        for (int nf = 0; nf < 8; nf++) {
            bf16x8 bh = *(const bf16x8*)(sBh + bRd[nf]);
            bf16x8 bl = *(const bf16x8*)(sBl + bRd[nf]);
#pragma unroll
            for (int mf = 0; mf < 4; mf++) {
                acc[mf][nf] = __builtin_amdgcn_mfma_f32_16x16x32_bf16(ah[mf], bh, acc[mf][nf], 0, 0, 0);
                acc[mf][nf] = __builtin_amdgcn_mfma_f32_16x16x32_bf16(ah[mf], bl, acc[mf][nf], 0, 0, 0);
                acc[mf][nf] = __builtin_amdgcn_mfma_f32_16x16x32_bf16(al[mf], bh, acc[mf][nf], 0, 0, 0);
            }
        }
    }

    // epilogue: C/D layout col=lane&15, row=(lane>>4)*4+r
#pragma unroll
    for (int mf = 0; mf < 4; mf++) {
        int r0 = bm + wm + mf * 16 + (lane >> 4) * 4;
#pragma unroll
        for (int nf = 0; nf < 8; nf++) {
            int c = bn + wn + nf * 16 + (lane & 15);
#pragma unroll
            for (int r = 0; r < 4; r++) {
                if (r0 + r < M) C[(size_t)(r0 + r) * GD + c] = acc[mf][nf][r];
            }
        }
    }
}

// ---------------- GCN aggregation (wave per row) + bf16 hi/lo split output ----------
__global__ __launch_bounds__(256) void agg_v2(const float* __restrict__ h,
                                              const int* __restrict__ row_ptr,
                                              const int* __restrict__ col,
                                              const float* __restrict__ dinv,
                                              const float* __restrict__ bias,
                                              unsigned short* __restrict__ out_hi,
                                              unsigned short* __restrict__ out_lo) {
    int wid = threadIdx.x >> 6, lane = threadIdx.x & 63;
    int row = blockIdx.x * 4 + wid;
    if (row >= NN) return;
    float di = dinv[row];
    const float4* hrow = (const float4*)(h + (size_t)row * GD);
    float4 s0 = hrow[lane * 2], s1 = hrow[lane * 2 + 1];
    float self = di * di;
    float a[8];
    a[0] = s0.x * self; a[1] = s0.y * self; a[2] = s0.z * self; a[3] = s0.w * self;
    a[4] = s1.x * self; a[5] = s1.y * self; a[6] = s1.z * self; a[7] = s1.w * self;

    int s = row_ptr[row], e = row_ptr[row + 1];
    int t = s;
    for (; t + 1 < e; t += 2) {
        int c0 = col[t], c1 = col[t + 1];
        float w0 = dinv[c0] * di, w1 = dinv[c1] * di;
        const float4* p0 = (const float4*)(h + (size_t)c0 * GD);
        const float4* p1 = (const float4*)(h + (size_t)c1 * GD);
        float4 v00 = p0[lane * 2], v01 = p0[lane * 2 + 1];
        float4 v10 = p1[lane * 2], v11 = p1[lane * 2 + 1];
        a[0] = fmaf(v00.x, w0, a[0]); a[1] = fmaf(v00.y, w0, a[1]);
        a[2] = fmaf(v00.z, w0, a[2]); a[3] = fmaf(v00.w, w0, a[3]);
        a[4] = fmaf(v01.x, w0, a[4]); a[5] = fmaf(v01.y, w0, a[5]);
        a[6] = fmaf(v01.z, w0, a[6]); a[7] = fmaf(v01.w, w0, a[7]);
        a[0] = fmaf(v10.x, w1, a[0]); a[1] = fmaf(v10.y, w1, a[1]);
        a[2] = fmaf(v10.z, w1, a[2]); a[3] = fmaf(v10.w, w1, a[3]);
        a[4] = fmaf(v11.x, w1, a[4]); a[5] = fmaf(v11.y, w1, a[5]);
        a[6] = fmaf(v11.z, w1, a[6]); a[7] = fmaf(v11.w, w1, a[7]);
    }
    if (t < e) {
        int c0 = col[t];
        float w0 = dinv[c0] * di;
        const float4* p0 = (const float4*)(h + (size_t)c0 * GD);
        float4 v00 = p0[lane * 2], v01 = p0[lane * 2 + 1];
        a[0] = fmaf(v00.x, w0, a[0]); a[1] = fmaf(v00.y, w0, a[1]);
        a[2] = fmaf(v00.z, w0, a[2]); a[3] = fmaf(v00.w, w0, a[3]);
        a[4] = fmaf(v01.x, w0, a[4]); a[5] = fmaf(v01.y, w0, a[5]);
        a[6] = fmaf(v01.z, w0, a[6]); a[7] = fmaf(v01.w, w0, a[7]);
    }

    const float4* b4 = (const float4*)bias;
    float4 b0 = b4[lane * 2], b1 = b4[lane * 2 + 1];
    a[0] += b0.x; a[1] += b0.y; a[2] += b0.z; a[3] += b0.w;
    a[4] += b1.x; a[5] += b1.y; a[6] += b1.z; a[7] += b1.w;

    ushort4 h4a, l4a, h4b, l4b;
    split_bf16(a[0], h4a.x, l4a.x); split_bf16(a[1], h4a.y, l4a.y);
    split_bf16(a[2], h4a.z, l4a.z); split_bf16(a[3], h4a.w, l4a.w);
    split_bf16(a[4], h4b.x, l4b.x); split_bf16(a[5], h4b.y, l4b.y);
    split_bf16(a[6], h4b.z, l4b.z); split_bf16(a[7], h4b.w, l4b.w);
    ((ushort4*)(out_hi + (size_t)row * GD))[lane * 2] = h4a;
    ((ushort4*)(out_hi + (size_t)row * GD))[lane * 2 + 1] = h4b;
    ((ushort4*)(out_lo + (size_t)row * GD))[lane * 2] = l4a;
    ((ushort4*)(out_lo + (size_t)row * GD))[lane * 2 + 1] = l4b;
}

// ---------------- mean-pool (sum phase, atomic into gsum) from hi/lo ------------
#define PCH 8
__global__ void pool_kernel(const unsigned short* __restrict__ hi,
                            const unsigned short* __restrict__ lo,
                            const int* __restrict__ goff,
                            float* __restrict__ gsum, int coloff) {
    int g = blockIdx.x;
    int c = blockIdx.y;
    int tid = threadIdx.x;
    int s = goff[g], e = goff[g + 1];
    long long len = e - s;
    int cs = s + (int)(len * c / PCH);
    int ce = s + (int)(len * (c + 1) / PCH);
    float a0 = 0.f, a1 = 0.f;
    for (int i = cs; i < ce; i++) {
        unsigned int uh = ((const unsigned int*)(hi + (size_t)i * GD))[tid];
        unsigned int ul = ((const unsigned int*)(lo + (size_t)i * GD))[tid];
        float v0 = __builtin_bit_cast(float, uh << 16) + __builtin_bit_cast(float, ul << 16);
        float v1 = __builtin_bit_cast(float, uh & 0xffff0000u) +
                   __builtin_bit_cast(float, ul & 0xffff0000u);
        a0 += v0;
        a1 += v1;
    }
    atomicAdd(&gsum[(size_t)g * CAT + coloff + tid * 2], a0);
    atomicAdd(&gsum[(size_t)g * CAT + coloff + tid * 2 + 1], a1);
}

__global__ void gdiv(float* __restrict__ gsum, const int* __restrict__ gcnt) {
    int i = blockIdx.x * 256 + threadIdx.x;
    if (i < NG * CAT) {
        int g = i / CAT;
        int c = gcnt[g];
        gsum[i] *= 1.0f / (float)(c > 0 ? c : 1);
    }
}

// ---------------- small FC: out[64 x NOUT] = act(A[64 x K] @ W + b) ----------------
template <int K, int NOUT, bool RELU>
__global__ __launch_bounds__(256) void fc_kernel(const float* __restrict__ A,
                                                 const float* __restrict__ W,
                                                 const float* __restrict__ bias,
                                                 float* __restrict__ out) {
    __shared__ float a_s[64][33];
    int tid = threadIdx.x;
    int c = blockIdx.x * 64 + (tid & 63);
    int grp = tid >> 6;
    float acc[16];
#pragma unroll
    for (int i = 0; i < 16; i++) acc[i] = 0.f;
    for (int k0 = 0; k0 < K; k0 += 32) {
        __syncthreads();
#pragma unroll
        for (int i = 0; i < 8; i++) {
            int idx = tid + i * 256;
            int m = idx >> 5, kk = idx & 31;
            a_s[m][kk] = A[(size_t)m * K + k0 + kk];
        }
        __syncthreads();
#pragma unroll
        for (int kk = 0; kk < 32; kk++) {
            float w = W[(size_t)(k0 + kk) * NOUT + c];
#pragma unroll
            for (int i = 0; i < 16; i++)
                acc[i] = fmaf(a_s[grp * 16 + i][kk], w, acc[i]);
        }
    }
    float b = bias[c];
#pragma unroll
    for (int i = 0; i < 16; i++) {
        float v = acc[i] + b;
        if (RELU) v = fmaxf(v, 0.f);
        out[(size_t)(grp * 16 + i) * NOUT + c] = v;
    }
}

// ---------------- launch ----------------
static inline size_t al256(size_t x) { return (x + 255) & ~(size_t)255; }

extern "C" void kernel_launch(void* const* d_in, const int* in_sizes, int n_in,
                              void* d_out, int out_size, void* d_ws, size_t ws_size,
                              hipStream_t stream) {
    const float* x   = (const float*)d_in[0];
    const int*   ei  = (const int*)d_in[1];
    const int*   bat = (const int*)d_in[2];
    const float* Wg1 = (const float*)d_in[3];
    const float* bg1 = (const float*)d_in[4];
    const float* Wg2 = (const float*)d_in[5];
    const float* bg2 = (const float*)d_in[6];
    const float* Wg3 = (const float*)d_in[7];
    const float* bg3 = (const float*)d_in[8];
    const float* Wr  = (const float*)d_in[9];
    const float* br  = (const float*)d_in[10];
    const float* Wf  = (const float*)d_in[11];
    const float* bf  = (const float*)d_in[12];
    const float* Wo  = (const float*)d_in[13];
    const float* bo  = (const float*)d_in[14];
    float* out = (float*)d_out;

    char* ws = (char*)d_ws;
    size_t off = 0;
    unsigned short* xhi = (unsigned short*)(ws + off); off += al256((size_t)NN * INDIM * 2);
    unsigned short* xlo = (unsigned short*)(ws + off); off += al256((size_t)NN * INDIM * 2);
    float* B0 = (float*)(ws + off); off += al256((size_t)NN * GD * 4);
    unsigned short* Bhi = (unsigned short*)(ws + off); off += al256((size_t)NN * GD * 2);
    unsigned short* Blo = (unsigned short*)(ws + off); off += al256((size_t)NN * GD * 2);
    unsigned short* Wt1h = (unsigned short*)(ws + off); off += al256((size_t)GD * INDIM * 2);
    unsigned short* Wt1l = (unsigned short*)(ws + off); off += al256((size_t)GD * INDIM * 2);
    unsigned short* Wt2h = (unsigned short*)(ws + off); off += al256((size_t)GD * GD * 2);
    unsigned short* Wt2l = (unsigned short*)(ws + off); off += al256((size_t)GD * GD * 2);
    unsigned short* Wt3h = (unsigned short*)(ws + off); off += al256((size_t)GD * GD * 2);
    unsigned short* Wt3l = (unsigned short*)(ws + off); off += al256((size_t)GD * GD * 2);
    int*   cnt = (int*)(ws + off); off += al256((size_t)NN * 4);
    int*   row_ptr = (int*)(ws + off); off += al256((size_t)(NN + 1) * 4);
    int*   fill = (int*)(ws + off); off += al256((size_t)NN * 4);
    float* dinv = (float*)(ws + off); off += al256((size_t)NN * 4);
    int*   col = (int*)(ws + off); off += al256((size_t)EE * 4);
    int*   bsum = (int*)(ws + off); off += al256(64 * 4);
    int*   gcnt = (int*)(ws + off); off += al256(NG * 4);
    int*   goff = (int*)(ws + off); off += al256((NG + 1) * 4);
    float* gsum = (float*)(ws + off); off += al256((size_t)NG * CAT * 4);
    float* r0 = (float*)(ws + off); off += al256((size_t)NG * FC0D * 4);
    float* r1 = (float*)(ws + off); off += al256((size_t)NG * FC1D * 4);
    (void)ws_size; (void)n_in; (void)in_sizes; (void)out_size;

    const int nscan = (NN + 1023) / 1024;

    // zero: cnt, gcnt, gsum
    zero_u32<<<dim3((NN + 255) / 256), 256, 0, stream>>>((uint32_t*)cnt, NN);
    zero_u32<<<dim3(1), 256, 0, stream>>>((uint32_t*)gcnt, NG);
    zero_u32<<<dim3((NG * CAT + 255) / 256), 256, 0, stream>>>((uint32_t*)gsum, NG * CAT);

    // CSR build (by dst)
    count_edges<<<dim3((EE + 255) / 256), 256, 0, stream>>>(ei, cnt);
    scan1<<<dim3(nscan), 1024, 0, stream>>>(cnt, row_ptr, bsum, NN);
    scan2<<<dim3(1), 64, 0, stream>>>(bsum, nscan);
    scan3<<<dim3(nscan), 1024, 0, stream>>>(row_ptr, bsum, NN);
    compute_dinv<<<dim3((NN + 255) / 256), 256, 0, stream>>>(cnt, dinv);
    copy_fill<<<dim3((NN + 255) / 256), 256, 0, stream>>>(row_ptr, fill);
    scatter_edges<<<dim3((EE + 255) / 256), 256, 0, stream>>>(ei, fill, col);

    // graph segments
    count_batch<<<dim3((NN + 255) / 256), 256, 0, stream>>>(bat, gcnt);
    gscan<<<dim3(1), 64, 0, stream>>>(gcnt, goff);

    // precompute: split x, transpose+split weights
    split_x_kernel<<<dim3(2048), 256, 0, stream>>>(x, xhi, xlo, NN * INDIM / 4);
    tsplit_kernel<<<dim3(INDIM / 32, GD / 32), 256, 0, stream>>>(Wg1, Wt1h, Wt1l, INDIM);
    tsplit_kernel<<<dim3(GD / 32, GD / 32), 256, 0, stream>>>(Wg2, Wt2h, Wt2l, GD);
    tsplit_kernel<<<dim3(GD / 32, GD / 32), 256, 0, stream>>>(Wg3, Wt3h, Wt3l, GD);

    dim3 ggrid((NN + GBM - 1) / GBM, GD / GBN);
    dim3 agrid((NN + 3) / 4);
    dim3 pgrid(NG, PCH);

    // Layer 1
    gemm_split<<<ggrid, 256, 0, stream>>>(xhi, xlo, Wt1h, Wt1l, B0, NN, INDIM);
    agg_v2<<<agrid, 256, 0, stream>>>(B0, row_ptr, col, dinv, bg1, Bhi, Blo);
    pool_kernel<<<pgrid, 256, 0, stream>>>(Bhi, Blo, goff, gsum, 0);
    // Layer 2
    gemm_split<<<ggrid, 256, 0, stream>>>(Bhi, Blo, Wt2h, Wt2l, B0, NN, GD);
    agg_v2<<<agrid, 256, 0, stream>>>(B0, row_ptr, col, dinv, bg2, Bhi, Blo);
    pool_kernel<<<pgrid, 256, 0, stream>>>(Bhi, Blo, goff, gsum, GD);
    // Layer 3
    gemm_split<<<ggrid, 256, 0, stream>>>(Bhi, Blo, Wt3h, Wt3l, B0, NN, GD);
    agg_v2<<<agrid, 256, 0, stream>>>(B0, row_ptr, col, dinv, bg3, Bhi, Blo);
    pool_kernel<<<pgrid, 256, 0, stream>>>(Bhi, Blo, goff, gsum, 2 * GD);

    // mean
    gdiv<<<dim3((NG * CAT + 255) / 256), 256, 0, stream>>>(gsum, gcnt);

    // FC head
    fc_kernel<CAT, FC0D, true><<<dim3(FC0D / 64), 256, 0, stream>>>(gsum, Wr, br, r0);
    fc_kernel<FC0D, FC1D, true><<<dim3(FC1D / 64), 256, 0, stream>>>(r0, Wf, bf, r1);
    fc_kernel<FC1D, OUTD, false><<<dim3(OUTD / 64), 256, 0, stream>>>(r1, Wo, bo, out);
}

// Round 3
// 1772.061 us; speedup vs baseline: 1.7602x; 1.2192x over previous
//
#include <hip/hip_runtime.h>
#include <stdint.h>

// Problem constants (fixed by the reference)
#define NN 50000
#define EE 800000
#define INDIM 1280
#define GD 512
#define CAT 1536
#define FC0D 1024
#define FC1D 512
#define OUTD 256
#define NG 64

typedef __attribute__((ext_vector_type(8))) __bf16 bf16x8;
typedef __attribute__((ext_vector_type(4))) float f32x4;
typedef __attribute__((ext_vector_type(8))) unsigned short u16x8;

// ---------------- helpers ----------------
__device__ __forceinline__ void split_bf16(float f, unsigned short& h, unsigned short& l) {
    unsigned int u = __builtin_bit_cast(unsigned int, f);
    h = (unsigned short)(u >> 16);                       // truncated hi
    float hf = __builtin_bit_cast(float, u & 0xffff0000u);
    float lf = f - hf;                                   // exact residual
    unsigned int ul = __builtin_bit_cast(unsigned int, lf);
    ul = ul + 0x7fffu + ((ul >> 16) & 1u);               // RNE lo
    l = (unsigned short)(ul >> 16);
}

__device__ __forceinline__ float bf2f(unsigned short s) {
    return __builtin_bit_cast(float, (unsigned int)s << 16);
}

__device__ __forceinline__ void g2l16(const void* g, void* l) {
    __builtin_amdgcn_global_load_lds(
        (const __attribute__((address_space(1))) void*)g,
        (__attribute__((address_space(3))) void*)l, 16, 0, 0);
}

// ---------------- utility kernels ----------------
__global__ void zero_u32(uint32_t* p, int n) {
    int i = blockIdx.x * 256 + threadIdx.x;
    if (i < n) p[i] = 0u;
}

__global__ void count_edges(const int* __restrict__ ei, int* __restrict__ cnt) {
    int e = blockIdx.x * 256 + threadIdx.x;
    if (e < EE) atomicAdd(&cnt[ei[EE + e]], 1);
}

__global__ __launch_bounds__(1024) void scan1(const int* __restrict__ cnt,
                                              int* __restrict__ row_ptr,
                                              int* __restrict__ bsum, int n) {
    __shared__ int s[1024];
    int tid = threadIdx.x;
    int i = blockIdx.x * 1024 + tid;
    int v = (i < n) ? cnt[i] : 0;
    s[tid] = v;
    __syncthreads();
    for (int off = 1; off < 1024; off <<= 1) {
        int t = 0;
        if (tid >= off) t = s[tid - off];
        __syncthreads();
        if (tid >= off) s[tid] += t;
        __syncthreads();
    }
    if (i < n) row_ptr[i] = s[tid] - v;
    if (tid == 1023) bsum[blockIdx.x] = s[1023];
}

// wave-parallel exclusive scan of nb (<=64) block sums
__global__ void scan2(int* bsum, int nb) {
    int i = threadIdx.x;   // 64 threads
    int v = (i < nb) ? bsum[i] : 0;
    int s = v;
#pragma unroll
    for (int off = 1; off < 64; off <<= 1) {
        int t = __shfl_up(s, off);
        if (i >= off) s += t;
    }
    if (i < nb) bsum[i] = s - v;
}

// row_ptr += block offset; also emit dinv and fill
__global__ __launch_bounds__(1024) void scan3(int* __restrict__ row_ptr,
                                              const int* __restrict__ bsum,
                                              const int* __restrict__ cnt,
                                              float* __restrict__ dinv,
                                              int* __restrict__ fill, int n) {
    int i = blockIdx.x * 1024 + threadIdx.x;
    if (i < n) {
        int rp = row_ptr[i] + bsum[blockIdx.x];
        row_ptr[i] = rp;
        fill[i] = rp;
        dinv[i] = rsqrtf((float)cnt[i] + 1.0f);
    }
    if (i == 0) row_ptr[n] = EE;
}

__global__ void scatter_edges(const int* __restrict__ ei, int* __restrict__ fill,
                              int* __restrict__ col) {
    int e = blockIdx.x * 256 + threadIdx.x;
    if (e < EE) {
        int s = ei[e];
        int d = ei[EE + e];
        int pos = atomicAdd(&fill[d], 1);
        col[pos] = s;
    }
}

__global__ void count_batch(const int* __restrict__ batch, int* __restrict__ gcnt) {
    int i = blockIdx.x * 256 + threadIdx.x;
    if (i < NN) atomicAdd(&gcnt[batch[i]], 1);
}

// wave-parallel scan of the 64 graph counts
__global__ void gscan(const int* __restrict__ gcnt, int* __restrict__ goff) {
    int i = threadIdx.x;   // 64 threads
    int v = gcnt[i];
    int s = v;
#pragma unroll
    for (int off = 1; off < 64; off <<= 1) {
        int t = __shfl_up(s, off);
        if (i >= off) s += t;
    }
    goff[i] = s - v;
    if (i == 63) goff[64] = s;
}

// ---------------- split fp32 -> bf16 hi/lo (flat) ----------------
__global__ void split_x_kernel(const float* __restrict__ x,
                               unsigned short* __restrict__ hi,
                               unsigned short* __restrict__ lo, int n4) {
    int stride = gridDim.x * 256;
    for (int i = blockIdx.x * 256 + threadIdx.x; i < n4; i += stride) {
        float4 v = ((const float4*)x)[i];
        ushort4 h4, l4;
        split_bf16(v.x, h4.x, l4.x);
        split_bf16(v.y, h4.y, l4.y);
        split_bf16(v.z, h4.z, l4.z);
        split_bf16(v.w, h4.w, l4.w);
        ((ushort4*)hi)[i] = h4;
        ((ushort4*)lo)[i] = l4;
    }
}

// ---------------- W [K][512] -> Wt hi/lo [512][K] (transpose + split) ----------------
__global__ __launch_bounds__(256) void tsplit_kernel(const float* __restrict__ W,
                                                     unsigned short* __restrict__ Thi,
                                                     unsigned short* __restrict__ Tlo,
                                                     int K) {
    __shared__ float t[32][33];
    int k0 = blockIdx.x * 32, n0 = blockIdx.y * 32;
    int r = threadIdx.x >> 3;
    int c4 = (threadIdx.x & 7) * 4;
    float4 v = *(const float4*)(W + (size_t)(k0 + r) * GD + n0 + c4);
    t[r][c4 + 0] = v.x;
    t[r][c4 + 1] = v.y;
    t[r][c4 + 2] = v.z;
    t[r][c4 + 3] = v.w;
    __syncthreads();
    ushort4 h4, l4;
    split_bf16(t[c4 + 0][r], h4.x, l4.x);
    split_bf16(t[c4 + 1][r], h4.y, l4.y);
    split_bf16(t[c4 + 2][r], h4.z, l4.z);
    split_bf16(t[c4 + 3][r], h4.w, l4.w);
    *(ushort4*)(Thi + (size_t)(n0 + r) * K + k0 + c4) = h4;
    *(ushort4*)(Tlo + (size_t)(n0 + r) * K + k0 + c4) = l4;
}

// ---------------- split-bf16 MFMA GEMM ----------------
// Out (pre-split bf16 hi/lo) = (Ahi+Alo)[M x K] @ (Whi+Wlo)[K x 512], W transposed [512][K].
// Block tile 128(M) x 256(N), BK=32, 256 threads = 4 waves, wave tile 64x128.
// 1-D grid with bijective XCD-chunked swizzle; w&1 selects the N-half so both
// halves of an A-panel run temporally adjacent on the same XCD (L2 reuse).
#define GBM 128
#define GBN 256
#define GBK 32

__global__ __launch_bounds__(256, 2) void gemm_split(
    const unsigned short* __restrict__ Ahi, const unsigned short* __restrict__ Alo,
    const unsigned short* __restrict__ Whi, const unsigned short* __restrict__ Wlo,
    unsigned short* __restrict__ Chi, unsigned short* __restrict__ Clo,
    int M, int K) {
    __shared__ __align__(16) char sAh[GBM * GBK * 2];   // 8 KB
    __shared__ __align__(16) char sAl[GBM * GBK * 2];   // 8 KB
    __shared__ __align__(16) char sBh[GBN * GBK * 2];   // 16 KB
    __shared__ __align__(16) char sBl[GBN * GBK * 2];   // 16 KB

    const int tid = threadIdx.x;
    const int lane = tid & 63, wid = tid >> 6;
    const int wm = (wid >> 1) * 64;
    const int wn = (wid & 1) * 128;

    // bijective XCD-chunked swizzle (m204)
    const int nwg = gridDim.x;
    const int q = nwg >> 3, r8 = nwg & 7;
    const int xcd = blockIdx.x & 7, slot = blockIdx.x >> 3;
    const int w = (xcd < r8 ? xcd * (q + 1) : r8 * (q + 1) + (xcd - r8) * q) + slot;
    const int bm = (w >> 1) * GBM;
    const int bn = (w & 1) * GBN;

    // --- staging source offsets (element units, bf16) ---
    int ar0 = tid >> 2;
    int ak0 = ((tid & 3) ^ ((ar0 >> 1) & 3)) * 8;
    int ar1 = (tid + 256) >> 2;
    int ak1 = ((tid & 3) ^ ((ar1 >> 1) & 3)) * 8;
    unsigned int aoff0 = (unsigned int)min(bm + ar0, M - 1) * K + ak0;
    unsigned int aoff1 = (unsigned int)min(bm + ar1, M - 1) * K + ak1;
    unsigned int woff[4];
#pragma unroll
    for (int i = 0; i < 4; i++) {
        int p = tid + i * 256;
        int row = p >> 2;
        int ks = ((p & 3) ^ ((row >> 1) & 3)) * 8;
        woff[i] = (unsigned int)(bn + row) * K + ks;
    }

    // --- LDS read byte offsets (swizzled), loop-invariant ---
    int aRd[4], bRd[8];
#pragma unroll
    for (int mf = 0; mf < 4; mf++) {
        int row = wm + mf * 16 + (lane & 15);
        aRd[mf] = row * 64 + ((((lane >> 4)) ^ ((row >> 1) & 3)) << 4);
    }
#pragma unroll
    for (int nf = 0; nf < 8; nf++) {
        int row = wn + nf * 16 + (lane & 15);
        bRd[nf] = row * 64 + ((((lane >> 4)) ^ ((row >> 1) & 3)) << 4);
    }

    f32x4 acc[4][8];
#pragma unroll
    for (int mf = 0; mf < 4; mf++)
#pragma unroll
        for (int nf = 0; nf < 8; nf++) acc[mf][nf] = (f32x4)0.0f;

    const int ldsw = wid * 1024;

    for (int k0 = 0; k0 < K; k0 += GBK) {
        __syncthreads();
        g2l16(Ahi + aoff0, sAh + ldsw);
        g2l16(Ahi + aoff1, sAh + 4096 + ldsw);
        g2l16(Alo + aoff0, sAl + ldsw);
        g2l16(Alo + aoff1, sAl + 4096 + ldsw);
#pragma unroll
        for (int i = 0; i < 4; i++) {
            g2l16(Whi + woff[i], sBh + i * 4096 + ldsw);
            g2l16(Wlo + woff[i], sBl + i * 4096 + ldsw);
        }
        aoff0 += GBK; aoff1 += GBK;
#pragma unroll
        for (int i = 0; i < 4; i++) woff[i] += GBK;
        __syncthreads();

        bf16x8 ah[4], al[4];
#pragma unroll
        for (int mf = 0; mf < 4; mf++) {
            ah[mf] = *(const bf16x8*)(sAh + aRd[mf]);
            al[mf] = *(const bf16x8*)(sAl + aRd[mf]);
        }
#pragma unroll
        for (int nf = 0; nf < 8; nf++) {
            bf16x8 bh = *(const bf16x8*)(sBh + bRd[nf]);
            bf16x8 bl = *(const bf16x8*)(sBl + bRd[nf]);
#pragma unroll
            for (int mf = 0; mf < 4; mf++) {
                acc[mf][nf] = __builtin_amdgcn_mfma_f32_16x16x32_bf16(ah[mf], bh, acc[mf][nf], 0, 0, 0);
                acc[mf][nf] = __builtin_amdgcn_mfma_f32_16x16x32_bf16(ah[mf], bl, acc[mf][nf], 0, 0, 0);
                acc[mf][nf] = __builtin_amdgcn_mfma_f32_16x16x32_bf16(al[mf], bh, acc[mf][nf], 0, 0, 0);
            }
        }
    }

    // epilogue: split to bf16 hi/lo, store. C/D layout col=lane&15, row=(lane>>4)*4+r
#pragma unroll
    for (int mf = 0; mf < 4; mf++) {
        int r0 = bm + wm + mf * 16 + (lane >> 4) * 4;
#pragma unroll
        for (int nf = 0; nf < 8; nf++) {
            int c = bn + wn + nf * 16 + (lane & 15);
#pragma unroll
            for (int r = 0; r < 4; r++) {
                if (r0 + r < M) {
                    unsigned short h, l;
                    split_bf16(acc[mf][nf][r], h, l);
                    Chi[(size_t)(r0 + r) * GD + c] = h;
                    Clo[(size_t)(r0 + r) * GD + c] = l;
                }
            }
        }
    }
}

// ---------------- GCN aggregation (wave per row) ----------------
// self term: full precision (Phi+Plo). neighbor gather: bf16 hi only (halves traffic).
// output: split bf16 hi/lo (feeds pool + next gemm).
__global__ __launch_bounds__(256) void agg_v3(const unsigned short* __restrict__ Phi,
                                              const unsigned short* __restrict__ Plo,
                                              const int* __restrict__ row_ptr,
                                              const int* __restrict__ col,
                                              const float* __restrict__ dinv,
                                              const float* __restrict__ bias,
                                              unsigned short* __restrict__ Ohi,
                                              unsigned short* __restrict__ Olo) {
    int wid = threadIdx.x >> 6, lane = threadIdx.x & 63;
    int row = blockIdx.x * 4 + wid;
    if (row >= NN) return;
    float di = dinv[row];
    float self = di * di;

    u16x8 sh = *(const u16x8*)(Phi + (size_t)row * GD + lane * 8);
    u16x8 sl = *(const u16x8*)(Plo + (size_t)row * GD + lane * 8);
    float a[8];
#pragma unroll
    for (int j = 0; j < 8; j++) a[j] = (bf2f(sh[j]) + bf2f(sl[j])) * self;

    int s = row_ptr[row], e = row_ptr[row + 1];
    int t = s;
    for (; t + 3 < e; t += 4) {
        int c0 = col[t], c1 = col[t + 1], c2 = col[t + 2], c3 = col[t + 3];
        float w0 = dinv[c0] * di, w1 = dinv[c1] * di;
        float w2 = dinv[c2] * di, w3 = dinv[c3] * di;
        u16x8 v0 = *(const u16x8*)(Phi + (size_t)c0 * GD + lane * 8);
        u16x8 v1 = *(const u16x8*)(Phi + (size_t)c1 * GD + lane * 8);
        u16x8 v2 = *(const u16x8*)(Phi + (size_t)c2 * GD + lane * 8);
        u16x8 v3 = *(const u16x8*)(Phi + (size_t)c3 * GD + lane * 8);
#pragma unroll
        for (int j = 0; j < 8; j++) {
            a[j] = fmaf(bf2f(v0[j]), w0, a[j]);
            a[j] = fmaf(bf2f(v1[j]), w1, a[j]);
            a[j] = fmaf(bf2f(v2[j]), w2, a[j]);
            a[j] = fmaf(bf2f(v3[j]), w3, a[j]);
        }
    }
    for (; t < e; t++) {
        int c0 = col[t];
        float w0 = dinv[c0] * di;
        u16x8 v0 = *(const u16x8*)(Phi + (size_t)c0 * GD + lane * 8);
#pragma unroll
        for (int j = 0; j < 8; j++) a[j] = fmaf(bf2f(v0[j]), w0, a[j]);
    }

    const float4* b4 = (const float4*)bias;
    float4 b0 = b4[lane * 2], b1 = b4[lane * 2 + 1];
    a[0] += b0.x; a[1] += b0.y; a[2] += b0.z; a[3] += b0.w;
    a[4] += b1.x; a[5] += b1.y; a[6] += b1.z; a[7] += b1.w;

    u16x8 oh, ol;
#pragma unroll
    for (int j = 0; j < 8; j++) {
        unsigned short h, l;
        split_bf16(a[j], h, l);
        oh[j] = h;
        ol[j] = l;
    }
    *(u16x8*)(Ohi + (size_t)row * GD + lane * 8) = oh;
    *(u16x8*)(Olo + (size_t)row * GD + lane * 8) = ol;
}

// ---------------- mean-pool (sum phase, atomic into gsum) from hi/lo ------------
#define PCH 32
__global__ void pool_kernel(const unsigned short* __restrict__ hi,
                            const unsigned short* __restrict__ lo,
                            const int* __restrict__ goff,
                            float* __restrict__ gsum, int coloff) {
    int g = blockIdx.x;
    int c = blockIdx.y;
    int tid = threadIdx.x;
    int s = goff[g], e = goff[g + 1];
    long long len = e - s;
    int cs = s + (int)(len * c / PCH);
    int ce = s + (int)(len * (c + 1) / PCH);
    float a0 = 0.f, a1 = 0.f;
    for (int i = cs; i < ce; i++) {
        unsigned int uh = ((const unsigned int*)(hi + (size_t)i * GD))[tid];
        unsigned int ul = ((const unsigned int*)(lo + (size_t)i * GD))[tid];
        float v0 = __builtin_bit_cast(float, uh << 16) + __builtin_bit_cast(float, ul << 16);
        float v1 = __builtin_bit_cast(float, uh & 0xffff0000u) +
                   __builtin_bit_cast(float, ul & 0xffff0000u);
        a0 += v0;
        a1 += v1;
    }
    if (cs < ce) {
        atomicAdd(&gsum[(size_t)g * CAT + coloff + tid * 2], a0);
        atomicAdd(&gsum[(size_t)g * CAT + coloff + tid * 2 + 1], a1);
    }
}

__global__ void gdiv(float* __restrict__ gsum, const int* __restrict__ gcnt) {
    int i = blockIdx.x * 256 + threadIdx.x;
    if (i < NG * CAT) {
        int g = i / CAT;
        int c = gcnt[g];
        gsum[i] *= 1.0f / (float)(c > 0 ? c : 1);
    }
}

// ---------------- small FC: out[64 x NOUT] = act(A[64 x K] @ W + b) ----------------
template <int K, int NOUT, bool RELU>
__global__ __launch_bounds__(256) void fc_kernel(const float* __restrict__ A,
                                                 const float* __restrict__ W,
                                                 const float* __restrict__ bias,
                                                 float* __restrict__ out) {
    __shared__ float a_s[64][33];
    int tid = threadIdx.x;
    int c = blockIdx.x * 64 + (tid & 63);
    int grp = tid >> 6;
    float acc[16];
#pragma unroll
    for (int i = 0; i < 16; i++) acc[i] = 0.f;
    for (int k0 = 0; k0 < K; k0 += 32) {
        __syncthreads();
#pragma unroll
        for (int i = 0; i < 8; i++) {
            int idx = tid + i * 256;
            int m = idx >> 5, kk = idx & 31;
            a_s[m][kk] = A[(size_t)m * K + k0 + kk];
        }
        __syncthreads();
#pragma unroll
        for (int kk = 0; kk < 32; kk++) {
            float w = W[(size_t)(k0 + kk) * NOUT + c];
#pragma unroll
            for (int i = 0; i < 16; i++)
                acc[i] = fmaf(a_s[grp * 16 + i][kk], w, acc[i]);
        }
    }
    float b = bias[c];
#pragma unroll
    for (int i = 0; i < 16; i++) {
        float v = acc[i] + b;
        if (RELU) v = fmaxf(v, 0.f);
        out[(size_t)(grp * 16 + i) * NOUT + c] = v;
    }
}

// ---------------- launch ----------------
static inline size_t al256(size_t x) { return (x + 255) & ~(size_t)255; }

extern "C" void kernel_launch(void* const* d_in, const int* in_sizes, int n_in,
                              void* d_out, int out_size, void* d_ws, size_t ws_size,
                              hipStream_t stream) {
    const float* x   = (const float*)d_in[0];
    const int*   ei  = (const int*)d_in[1];
    const int*   bat = (const int*)d_in[2];
    const float* Wg1 = (const float*)d_in[3];
    const float* bg1 = (const float*)d_in[4];
    const float* Wg2 = (const float*)d_in[5];
    const float* bg2 = (const float*)d_in[6];
    const float* Wg3 = (const float*)d_in[7];
    const float* bg3 = (const float*)d_in[8];
    const float* Wr  = (const float*)d_in[9];
    const float* br  = (const float*)d_in[10];
    const float* Wf  = (const float*)d_in[11];
    const float* bf  = (const float*)d_in[12];
    const float* Wo  = (const float*)d_in[13];
    const float* bo  = (const float*)d_in[14];
    float* out = (float*)d_out;

    char* ws = (char*)d_ws;
    size_t off = 0;
    unsigned short* xhi = (unsigned short*)(ws + off); off += al256((size_t)NN * INDIM * 2);
    unsigned short* xlo = (unsigned short*)(ws + off); off += al256((size_t)NN * INDIM * 2);
    unsigned short* Phi = (unsigned short*)(ws + off); off += al256((size_t)NN * GD * 2);
    unsigned short* Plo = (unsigned short*)(ws + off); off += al256((size_t)NN * GD * 2);
    unsigned short* Ohi = (unsigned short*)(ws + off); off += al256((size_t)NN * GD * 2);
    unsigned short* Olo = (unsigned short*)(ws + off); off += al256((size_t)NN * GD * 2);
    unsigned short* Wt1h = (unsigned short*)(ws + off); off += al256((size_t)GD * INDIM * 2);
    unsigned short* Wt1l = (unsigned short*)(ws + off); off += al256((size_t)GD * INDIM * 2);
    unsigned short* Wt2h = (unsigned short*)(ws + off); off += al256((size_t)GD * GD * 2);
    unsigned short* Wt2l = (unsigned short*)(ws + off); off += al256((size_t)GD * GD * 2);
    unsigned short* Wt3h = (unsigned short*)(ws + off); off += al256((size_t)GD * GD * 2);
    unsigned short* Wt3l = (unsigned short*)(ws + off); off += al256((size_t)GD * GD * 2);
    int*   cnt = (int*)(ws + off); off += al256((size_t)NN * 4);
    int*   row_ptr = (int*)(ws + off); off += al256((size_t)(NN + 1) * 4);
    int*   fill = (int*)(ws + off); off += al256((size_t)NN * 4);
    float* dinv = (float*)(ws + off); off += al256((size_t)NN * 4);
    int*   col = (int*)(ws + off); off += al256((size_t)EE * 4);
    int*   bsum = (int*)(ws + off); off += al256(64 * 4);
    int*   gcnt = (int*)(ws + off); off += al256(NG * 4);
    int*   goff = (int*)(ws + off); off += al256((NG + 1) * 4);
    float* gsum = (float*)(ws + off); off += al256((size_t)NG * CAT * 4);
    float* r0 = (float*)(ws + off); off += al256((size_t)NG * FC0D * 4);
    float* r1 = (float*)(ws + off); off += al256((size_t)NG * FC1D * 4);
    (void)ws_size; (void)n_in; (void)in_sizes; (void)out_size;

    const int nscan = (NN + 1023) / 1024;

    // zero: cnt, gcnt, gsum
    zero_u32<<<dim3((NN + 255) / 256), 256, 0, stream>>>((uint32_t*)cnt, NN);
    zero_u32<<<dim3(1), 256, 0, stream>>>((uint32_t*)gcnt, NG);
    zero_u32<<<dim3((NG * CAT + 255) / 256), 256, 0, stream>>>((uint32_t*)gsum, NG * CAT);

    // CSR build (by dst)
    count_edges<<<dim3((EE + 255) / 256), 256, 0, stream>>>(ei, cnt);
    scan1<<<dim3(nscan), 1024, 0, stream>>>(cnt, row_ptr, bsum, NN);
    scan2<<<dim3(1), 64, 0, stream>>>(bsum, nscan);
    scan3<<<dim3(nscan), 1024, 0, stream>>>(row_ptr, bsum, cnt, dinv, fill, NN);
    scatter_edges<<<dim3((EE + 255) / 256), 256, 0, stream>>>(ei, fill, col);

    // graph segments
    count_batch<<<dim3((NN + 255) / 256), 256, 0, stream>>>(bat, gcnt);
    gscan<<<dim3(1), 64, 0, stream>>>(gcnt, goff);

    // precompute: split x, transpose+split weights
    split_x_kernel<<<dim3(2048), 256, 0, stream>>>(x, xhi, xlo, NN * INDIM / 4);
    tsplit_kernel<<<dim3(INDIM / 32, GD / 32), 256, 0, stream>>>(Wg1, Wt1h, Wt1l, INDIM);
    tsplit_kernel<<<dim3(GD / 32, GD / 32), 256, 0, stream>>>(Wg2, Wt2h, Wt2l, GD);
    tsplit_kernel<<<dim3(GD / 32, GD / 32), 256, 0, stream>>>(Wg3, Wt3h, Wt3l, GD);

    const int nwg = ((NN + GBM - 1) / GBM) * (GD / GBN);   // 782
    dim3 ggrid(nwg);
    dim3 agrid((NN + 3) / 4);
    dim3 pgrid(NG, PCH);

    // Layer 1
    gemm_split<<<ggrid, 256, 0, stream>>>(xhi, xlo, Wt1h, Wt1l, Phi, Plo, NN, INDIM);
    agg_v3<<<agrid, 256, 0, stream>>>(Phi, Plo, row_ptr, col, dinv, bg1, Ohi, Olo);
    pool_kernel<<<pgrid, 256, 0, stream>>>(Ohi, Olo, goff, gsum, 0);
    // Layer 2
    gemm_split<<<ggrid, 256, 0, stream>>>(Ohi, Olo, Wt2h, Wt2l, Phi, Plo, NN, GD);
    agg_v3<<<agrid, 256, 0, stream>>>(Phi, Plo, row_ptr, col, dinv, bg2, Ohi, Olo);
    pool_kernel<<<pgrid, 256, 0, stream>>>(Ohi, Olo, goff, gsum, GD);
    // Layer 3
    gemm_split<<<ggrid, 256, 0, stream>>>(Ohi, Olo, Wt3h, Wt3l, Phi, Plo, NN, GD);
    agg_v3<<<agrid, 256, 0, stream>>>(Phi, Plo, row_ptr, col, dinv, bg3, Ohi, Olo);
    pool_kernel<<<pgrid, 256, 0, stream>>>(Ohi, Olo, goff, gsum, 2 * GD);

    // mean
    gdiv<<<dim3((NG * CAT + 255) / 256), 256, 0, stream>>>(gsum, gcnt);

    // FC head
    fc_kernel<CAT, FC0D, true><<<dim3(FC0D / 64), 256, 0, stream>>>(gsum, Wr, br, r0);
    fc_kernel<FC0D, FC1D, true><<<dim3(FC1D / 64), 256, 0, stream>>>(r0, Wf, bf, r1);
    fc_kernel<FC1D, OUTD, false><<<dim3(OUTD / 64), 256, 0, stream>>>(r1, Wo, bo, out);
}